// Round 10
// baseline (30.468 us; speedup 1.0000x reference)
//
#include <hip/hip_runtime.h>
#include <stdint.h>

#define NB   32768
#define NIN  64
#define NOUT 32
// ws layout (bytes)
#define OFF_PMIN 0          // 64*64*4 = 16384
#define OFF_PMAX 16384      // 16384
#define OFF_CSW  32768      // 2560*32*2 = 163840 (16B aligned)

typedef __bf16 bf16x8 __attribute__((ext_vector_type(8)));
typedef float  f32x4  __attribute__((ext_vector_type(4)));

__device__ __forceinline__ float softplus_f(float x) {
  return fmaxf(x, 0.0f) + log1pf(expf(-fabsf(x)));
}

// ---------------- kernel 1: fused prep ----------------
// blocks 0-63:  per-feature min/max partials (512 rows each)
// blocks 64-71: folded coefficients -> Csw (independent of minmax)
// 40-slot basis per feature (5 bf16x8 groups):
//  g0: bsp0..7 | g1: bsp8..10, x, x^2, x^3, x^4, 1 | g2: cos1..8 | g3: sin1..8 | g4: wav0..3,0*4
// frag unit (bf16x8): ((wv*20 + cc*5 + s)*4 + kgi)*32 + o   for feature i = wv*16+kgi*4+cc.
__global__ __launch_bounds__(256) void k_prep(const float* __restrict__ X,
                                              const float* __restrict__ base_v,
                                              const float* __restrict__ base_g,
                                              const float* __restrict__ bsp,
                                              const float* __restrict__ tay,
                                              const float* __restrict__ jac,
                                              const float* __restrict__ che,
                                              const float* __restrict__ fou,
                                              const float* __restrict__ wav,
                                              const float* __restrict__ gains,
                                              const float* __restrict__ alpha,
                                              const float* __restrict__ beta,
                                              const float* __restrict__ mixl,
                                              float* __restrict__ pmin,
                                              float* __restrict__ pmax,
                                              unsigned short* __restrict__ Csw) {
  int t = threadIdx.x;
  if (blockIdx.x < 64) {
    const float4* X4 = (const float4*)X;
    int g = t & 15, r = t >> 4;
    float4 lo = {3.402823466e38f, 3.402823466e38f, 3.402823466e38f, 3.402823466e38f};
    float4 hi = {-3.402823466e38f, -3.402823466e38f, -3.402823466e38f, -3.402823466e38f};
    int base = blockIdx.x * 8192;  // 512 rows * 16 f4
    #pragma unroll 8
    for (int k = 0; k < 32; ++k) {
      float4 v = X4[base + k * 256 + t];
      lo.x = fminf(lo.x, v.x); lo.y = fminf(lo.y, v.y);
      lo.z = fminf(lo.z, v.z); lo.w = fminf(lo.w, v.w);
      hi.x = fmaxf(hi.x, v.x); hi.y = fmaxf(hi.y, v.y);
      hi.z = fmaxf(hi.z, v.z); hi.w = fmaxf(hi.w, v.w);
    }
    __shared__ float4 slo[16][16], shi[16][16];
    slo[r][g] = lo; shi[r][g] = hi;
    __syncthreads();
    if (t < 64) {
      int gg = t >> 2, c = t & 3;
      float l = 3.402823466e38f, h = -3.402823466e38f;
      #pragma unroll
      for (int rr = 0; rr < 16; ++rr) {
        const float* pl = (const float*)&slo[rr][gg];
        const float* ph = (const float*)&shi[rr][gg];
        l = fminf(l, pl[c]); h = fmaxf(h, ph[c]);
      }
      pmin[blockIdx.x * 64 + t] = l;
      pmax[blockIdx.x * 64 + t] = h;
    }
  } else {
    int o = (blockIdx.x - 64) * 4 + (t >> 6);
    int i = t & 63;
    int p = o * 64 + i;
    float spa = softplus_f(alpha[0]);
    float spb = softplus_f(beta[0]);
    float spg[6];
    #pragma unroll
    for (int f = 0; f < 6; ++f) spg[f] = softplus_f(gains[f]);
    float m[6], mmax = -3.402823466e38f;
    #pragma unroll
    for (int f = 0; f < 6; ++f) { m[f] = mixl[p * 6 + f] * 0.5f; mmax = fmaxf(mmax, m[f]); }
    float es = 0.f;
    #pragma unroll
    for (int f = 0; f < 6; ++f) { m[f] = __expf(m[f] - mmax); es += m[f]; }
    float inv = 1.0f / es;

    float vv = base_v[p];
    float s2 = vv * vv;
    #pragma unroll
    for (int d = 1; d < 64; d <<= 1) s2 += __shfl_xor(s2, d);
    float vn = sqrtf(s2);
    float Wid = spa * base_g[o] * vv / vn;   // identity path: sp(alpha)*W[o,i]

    float wB = spb * spg[0] * m[0] * inv;
    float wT = spb * spg[1] * m[1] * inv;
    float wJ = spb * spg[2] * m[2] * inv;
    float wC = spb * spg[3] * m[3] * inv;
    float wF = spb * spg[4] * m[4] * inv * 0.25f;
    float wW = spb * spg[5] * m[5] * inv;

    float j0 = jac[p * 5 + 0], j1 = jac[p * 5 + 1], j2 = jac[p * 5 + 2],
          j3 = jac[p * 5 + 3], j4 = jac[p * 5 + 4];
    float c0 = che[p * 5 + 0], c1 = che[p * 5 + 1], c2 = che[p * 5 + 2],
          c3 = che[p * 5 + 3], c4 = che[p * 5 + 4];
    float t0 = tay[p * 4 + 0], t1 = tay[p * 4 + 1], t2 = tay[p * 4 + 2], t3 = tay[p * 4 + 3];

    float slot[40];
    #pragma unroll
    for (int k = 0; k < 11; ++k) slot[k] = wB * bsp[p * 11 + k];
    // monomial folds (verified vs reference recurrences)
    slot[11] = Wid + wT * t1
             + wJ * (1.4142136f * j1 - 0.7619780f * j3)
             + wC * (0.7071068f * c1 - 1.5f * c3);                       // x
    slot[12] = wT * 0.5f * t2
             + wJ * (1.2247449f * j2 - 0.9736894f * j4)
             + wC * (1.1547005f * c2 - 3.5777088f * c4);                 // x^2
    slot[13] = wT * (1.0f / 6.0f) * t3
             + wJ * 0.9797959f * j3
             + wC * 2.0f * c3;                                           // x^3
    slot[14] = wJ * 0.7302967f * j4 + wC * 3.5777088f * c4;              // x^4
    slot[15] = wT * t0
             + wJ * (j0 - 0.3464102f * j2 + 0.1147551f * j4)
             + wC * (c0 - 0.5773503f * c2 + 0.4472136f * c4);            // 1
    #pragma unroll
    for (int k = 0; k < 8; ++k) slot[16 + k] = wF * fou[p * 16 + k];      // cos
    #pragma unroll
    for (int k = 0; k < 8; ++k) slot[24 + k] = wF * fou[p * 16 + 8 + k];  // sin
    #pragma unroll
    for (int k = 0; k < 4; ++k) slot[32 + k] = wW * wav[p * 4 + k];
    slot[36] = 0.f; slot[37] = 0.f; slot[38] = 0.f; slot[39] = 0.f;

    int wv = i >> 4, kgi = (i >> 2) & 3, cc = i & 3;
    bf16x8* CBo = reinterpret_cast<bf16x8*>(Csw);
    #pragma unroll
    for (int s = 0; s < 5; ++s) {
      bf16x8 pk;
      #pragma unroll
      for (int j = 0; j < 8; ++j) pk[j] = (__bf16)slot[s * 8 + j];
      int st = wv * 20 + cc * 5 + s;
      CBo[(st * 4 + kgi) * 32 + o] = pk;
    }
  }
}

// ---------------- 40-slot basis -> 5 A-fragments (scalar, proven numerics) ----------------
__device__ __forceinline__ void basis40(float x, float4 q0, float4 q1, float4 q2,
                                        bf16x8& A0, bf16x8& A1, bf16x8& A2,
                                        bf16x8& A3, bf16x8& A4) {
  // ---- B-spline, normalized coords: u in [0,8], integer knots ----
  {
    float u = (x - q0.x) * q0.y;
    int ji = (int)u;
    float e0 = (ji == 0) ? 1.f : 0.f;
    float e1 = (ji == 1) ? 1.f : 0.f;
    float e2 = (ji == 2) ? 1.f : 0.f;
    float e3 = (ji == 3) ? 1.f : 0.f;
    float e4 = (ji == 4) ? 1.f : 0.f;
    float e5 = (ji == 5) ? 1.f : 0.f;
    float e6 = (ji == 6) ? 1.f : 0.f;
    float e7 = (ji == 7) ? 1.f : 0.f;
    float d0 = u,       d1 = u - 1.f, d2 = u - 2.f, d3 = u - 3.f, d4 = u - 4.f;
    float d5 = u - 5.f, d6 = u - 6.f, d7 = u - 7.f, d8 = u - 8.f;
    float a2 = -d1 * e0;
    float a3 = d0 * e0 - d2 * e1;
    float a4 = d1 * e1 - d3 * e2;
    float a5 = d2 * e2 - d4 * e3;
    float a6 = d3 * e3 - d5 * e4;
    float a7 = d4 * e4 - d6 * e5;
    float a8 = d5 * e5 - d7 * e6;
    float a9 = d6 * e6 - d8 * e7;
    float a10 = d7 * e7;
    float h0 = 0.5f * d0, h1 = 0.5f * d1, h2 = 0.5f * d2, h3 = 0.5f * d3, h4 = 0.5f * d4;
    float h5 = 0.5f * d5, h6 = 0.5f * d6, h7 = 0.5f * d7, h8 = 0.5f * d8;
    float c1v = -d1 * a2;
    float c2v = d0 * a2 - h2 * a3;
    float c3v = h0 * a3 - h3 * a4;
    float c4v = h1 * a4 - h4 * a5;
    float c5v = h2 * a5 - h5 * a6;
    float c6v = h3 * a6 - h6 * a7;
    float c7v = h4 * a7 - h7 * a8;
    float c8v = h5 * a8 - h8 * a9;
    float c9v = h6 * a9 - d8 * a10;
    float c10v = d7 * a10;
    const float TH = 0.33333333333333f;
    A0[0] = (__bf16)(-d1 * c1v);
    A0[1] = (__bf16)(d0 * c1v - h2 * c2v);
    A0[2] = (__bf16)(h0 * c2v - TH * (d3 * c3v));
    A0[3] = (__bf16)((d0 * c3v - d4 * c4v) * TH);
    A0[4] = (__bf16)((d1 * c4v - d5 * c5v) * TH);
    A0[5] = (__bf16)((d2 * c5v - d6 * c6v) * TH);
    A0[6] = (__bf16)((d3 * c6v - d7 * c7v) * TH);
    A0[7] = (__bf16)((d4 * c7v - d8 * c8v) * TH);
    A1[0] = (__bf16)(TH * (d5 * c8v) - h8 * c9v);
    A1[1] = (__bf16)(h6 * c9v - d8 * c10v);
    A1[2] = (__bf16)(d7 * c10v);
  }
  // ---- monomials x, x^2, x^3, x^4, 1 ----
  {
    float x2 = x * x, x3v = x2 * x, x4v = x2 * x2;
    A1[3] = (__bf16)x;
    A1[4] = (__bf16)x2;
    A1[5] = (__bf16)x3v;
    A1[6] = (__bf16)x4v;
    A1[7] = (__bf16)1.0f;
  }
  // ---- Fourier cos1..8 / sin1..8 (angle-doubling tree) ----
  {
    float s1 = __sinf(x), c1f = __cosf(x);
    float c2f = 2.0f * c1f * c1f - 1.0f, s2f = 2.0f * s1 * c1f;
    float c3f = c2f * c1f - s2f * s1,    s3f = s2f * c1f + c2f * s1;
    float c4f = 2.0f * c2f * c2f - 1.0f, s4f = 2.0f * s2f * c2f;
    float c5f = c4f * c1f - s4f * s1,    s5f = s4f * c1f + c4f * s1;
    float c6f = c4f * c2f - s4f * s2f,   s6f = s4f * c2f + c4f * s2f;
    float c7f = c4f * c3f - s4f * s3f,   s7f = s4f * c3f + c4f * s3f;
    float c8f = 2.0f * c4f * c4f - 1.0f, s8f = 2.0f * s4f * c4f;
    A2[0] = (__bf16)c1f; A2[1] = (__bf16)c2f; A2[2] = (__bf16)c3f; A2[3] = (__bf16)c4f;
    A2[4] = (__bf16)c5f; A2[5] = (__bf16)c6f; A2[6] = (__bf16)c7f; A2[7] = (__bf16)c8f;
    A3[0] = (__bf16)s1;  A3[1] = (__bf16)s2f; A3[2] = (__bf16)s3f; A3[3] = (__bf16)s4f;
    A3[4] = (__bf16)s5f; A3[5] = (__bf16)s6f; A3[6] = (__bf16)s7f; A3[7] = (__bf16)s8f;
  }
  // ---- Wavelet ----
  {
    float u0 = (x - q1.z) * q0.z, u1 = (x - q1.w) * q0.w;
    float u2 = (x - q2.x) * q1.x, u3 = (x - q2.y) * q1.y;
    float s0 = u0 * u0, s1w = u1 * u1, s2w = u2 * u2, s3 = u3 * u3;
    A4[0] = (__bf16)((s0 - 1.0f) * __expf(-0.5f * s0));
    A4[1] = (__bf16)((s1w - 1.0f) * __expf(-0.5f * s1w));
    A4[2] = (__bf16)((s2w - 1.0f) * __expf(-0.5f * s2w));
    A4[3] = (__bf16)((s3 - 1.0f) * __expf(-0.5f * s3));
    A4[4] = (__bf16)0.0f; A4[5] = (__bf16)0.0f;
    A4[6] = (__bf16)0.0f; A4[7] = (__bf16)0.0f;
  }
}

// ---------------- kernel 2: main fused kernel (quad sample tile) ----------------
// 256 threads = 4 waves, FOUR 16-sample tiles (64 samples/block, grid 512 = 2
// blocks/CU resident in one round), K-split 4 ways. All tiles share one set of
// B fragments per pass -> B traffic halved vs 2-tile. Scalar basis (R8-proven;
// packed f32x2 math mis-codegens, R9). One barrier for the K-reduction.
__global__ __launch_bounds__(256) void k_main(const float* __restrict__ X,
                                              const unsigned short* __restrict__ Csw,
                                              const float* __restrict__ pmin,
                                              const float* __restrict__ pmax,
                                              const float* __restrict__ wscale,
                                              const float* __restrict__ wshift,
                                              const float* __restrict__ alpha,
                                              const float* __restrict__ bias,
                                              float* __restrict__ out) {
  __shared__ float red[3][2048];
  __shared__ float slo[4][64], shi[4][64];
  __shared__ float featL[64][12];
  __shared__ float ebL[32];

  int t = threadIdx.x;
  int w = t >> 6, lane = t & 63;
  int col = lane & 15, kg = lane >> 4;
  int sbase = blockIdx.x * 64;

  // issue global loads first; they fly under the prelude
  const float4* X4 = (const float4*)X;
  float4 xq0 = X4[(sbase + col) * 16 + w * 4 + kg];
  float4 xq1 = X4[(sbase + 16 + col) * 16 + w * 4 + kg];
  float4 xq2 = X4[(sbase + 32 + col) * 16 + w * 4 + kg];
  float4 xq3 = X4[(sbase + 48 + col) * 16 + w * 4 + kg];
  float xr0[4] = {xq0.x, xq0.y, xq0.z, xq0.w};
  float xr1[4] = {xq1.x, xq1.y, xq1.z, xq1.w};
  float xr2[4] = {xq2.x, xq2.y, xq2.z, xq2.w};
  float xr3[4] = {xq3.x, xq3.y, xq3.z, xq3.w};

  const bf16x8* CB = reinterpret_cast<const bf16x8*>(Csw);
  const bf16x8* CBw = CB + (size_t)w * 2560 + kg * 32;
  bf16x8 B0, B1, B2, B3, B4, B5, B6, B7, B8, B9;
#define LOADB(cc) do { const bf16x8* p_ = CBw + (size_t)(cc) * 640;            \
    B0 = p_[col];        B1 = p_[col + 16];                                    \
    B2 = p_[128 + col];  B3 = p_[128 + col + 16];                              \
    B4 = p_[256 + col];  B5 = p_[256 + col + 16];                              \
    B6 = p_[384 + col];  B7 = p_[384 + col + 16];                              \
    B8 = p_[512 + col];  B9 = p_[512 + col + 16]; } while (0)
  LOADB(0);

  // ---- prelude: feature params ----
  {
    int f = t & 63, q = t >> 6;
    float lo = 3.402823466e38f, hi = -3.402823466e38f;
    #pragma unroll
    for (int pp = 0; pp < 16; ++pp) {
      int p = q * 16 + pp;
      lo = fminf(lo, pmin[p * 64 + f]);
      hi = fmaxf(hi, pmax[p * 64 + f]);
    }
    slo[q][f] = lo; shi[q][f] = hi;
  }
  __syncthreads();
  if (t < 64) {
    float lo = fminf(fminf(slo[0][t], slo[1][t]), fminf(slo[2][t], slo[3][t]));
    float hi = fmaxf(fmaxf(shi[0][t], shi[1][t]), fmaxf(shi[2][t], shi[3][t]));
    if (hi - lo < 1e-8f) { lo = lo - 0.5f; hi = hi + 0.5f; }
    float d = hi - lo;
    featL[t][0] = lo;
    featL[t][1] = 8.0f / d;
    #pragma unroll
    for (int c = 0; c < 4; ++c) {
      float a = softplus_f(wscale[t * 4 + c]) + 1e-6f;
      featL[t][2 + c] = 1.0f / a;
      featL[t][6 + c] = wshift[t * 4 + c];
    }
    featL[t][10] = 0.f; featL[t][11] = 0.f;
  }
  if (t >= 128 && t < 160) {
    int o = t - 128;
    ebL[o] = softplus_f(alpha[0]) * bias[o];
  }
  __syncthreads();

  f32x4 acc00 = {0.f,0.f,0.f,0.f}, acc01 = {0.f,0.f,0.f,0.f};
  f32x4 acc10 = {0.f,0.f,0.f,0.f}, acc11 = {0.f,0.f,0.f,0.f};
  f32x4 acc20 = {0.f,0.f,0.f,0.f}, acc21 = {0.f,0.f,0.f,0.f};
  f32x4 acc30 = {0.f,0.f,0.f,0.f}, acc31 = {0.f,0.f,0.f,0.f};

#define TILE(xv, a0, a1)                                                       \
  do {                                                                         \
    bf16x8 A0, A1, A2, A3, A4;                                                 \
    basis40(xv, q0, q1, q2, A0, A1, A2, A3, A4);                               \
    a0 = __builtin_amdgcn_mfma_f32_16x16x32_bf16(A0, B0, a0, 0, 0, 0);         \
    a1 = __builtin_amdgcn_mfma_f32_16x16x32_bf16(A0, B1, a1, 0, 0, 0);         \
    a0 = __builtin_amdgcn_mfma_f32_16x16x32_bf16(A1, B2, a0, 0, 0, 0);         \
    a1 = __builtin_amdgcn_mfma_f32_16x16x32_bf16(A1, B3, a1, 0, 0, 0);         \
    a0 = __builtin_amdgcn_mfma_f32_16x16x32_bf16(A2, B4, a0, 0, 0, 0);         \
    a1 = __builtin_amdgcn_mfma_f32_16x16x32_bf16(A2, B5, a1, 0, 0, 0);         \
    a0 = __builtin_amdgcn_mfma_f32_16x16x32_bf16(A3, B6, a0, 0, 0, 0);         \
    a1 = __builtin_amdgcn_mfma_f32_16x16x32_bf16(A3, B7, a1, 0, 0, 0);         \
    a0 = __builtin_amdgcn_mfma_f32_16x16x32_bf16(A4, B8, a0, 0, 0, 0);         \
    a1 = __builtin_amdgcn_mfma_f32_16x16x32_bf16(A4, B9, a1, 0, 0, 0);         \
  } while (0)

  #pragma unroll 1
  for (int c = 0; c < 4; ++c) {
    int f = w * 16 + kg * 4 + c;
    const float4* fq = (const float4*)&featL[f][0];
    float4 q0 = fq[0];   // xmin, ih, inva0, inva1
    float4 q1 = fq[1];   // inva2, inva3, shift0, shift1
    float4 q2 = fq[2];   // shift2, shift3, -, -

    TILE(xr0[c], acc00, acc01);
    TILE(xr1[c], acc10, acc11);
    TILE(xr2[c], acc20, acc21);
    TILE(xr3[c], acc30, acc31);

    if (c < 3) LOADB(c + 1);   // hides under next pass's basis compute
  }
#undef TILE
#undef LOADB

  // ---- 4-way cross-wave K-reduction (single barrier) ----
  if (w > 0) {
    float* rw = &red[w - 1][0];
    #pragma unroll
    for (int j = 0; j < 4; ++j) {
      int idx = (kg * 4 + j) * 32 + col;
      rw[idx]             = acc00[j];
      rw[idx + 16]        = acc01[j];
      rw[512 + idx]       = acc10[j];
      rw[512 + idx + 16]  = acc11[j];
      rw[1024 + idx]      = acc20[j];
      rw[1024 + idx + 16] = acc21[j];
      rw[1536 + idx]      = acc30[j];
      rw[1536 + idx + 16] = acc31[j];
    }
  }
  __syncthreads();
  if (w == 0) {
    float eb0 = ebL[col], eb1 = ebL[col + 16];
    #pragma unroll
    for (int j = 0; j < 4; ++j) {
      int idx0 = (kg * 4 + j) * 32 + col;
      int idx1 = idx0 + 16;
      int row = sbase + kg * 4 + j;
      out[row * 32 + col]      = acc00[j] + red[0][idx0] + red[1][idx0] + red[2][idx0] + eb0;
      out[row * 32 + col + 16] = acc01[j] + red[0][idx1] + red[1][idx1] + red[2][idx1] + eb1;
      out[(row + 16) * 32 + col]      = acc10[j] + red[0][512 + idx0] + red[1][512 + idx0] + red[2][512 + idx0] + eb0;
      out[(row + 16) * 32 + col + 16] = acc11[j] + red[0][512 + idx1] + red[1][512 + idx1] + red[2][512 + idx1] + eb1;
      out[(row + 32) * 32 + col]      = acc20[j] + red[0][1024 + idx0] + red[1][1024 + idx0] + red[2][1024 + idx0] + eb0;
      out[(row + 32) * 32 + col + 16] = acc21[j] + red[0][1024 + idx1] + red[1][1024 + idx1] + red[2][1024 + idx1] + eb1;
      out[(row + 48) * 32 + col]      = acc30[j] + red[0][1536 + idx0] + red[1][1536 + idx0] + red[2][1536 + idx0] + eb0;
      out[(row + 48) * 32 + col + 16] = acc31[j] + red[0][1536 + idx1] + red[1][1536 + idx1] + red[2][1536 + idx1] + eb1;
    }
  }
}

extern "C" void kernel_launch(void* const* d_in, const int* in_sizes, int n_in,
                              void* d_out, int out_size, void* d_ws, size_t ws_size,
                              hipStream_t stream) {
  const float* X   = (const float*)d_in[0];
  const float* bv  = (const float*)d_in[1];
  const float* bg  = (const float*)d_in[2];
  const float* bbi = (const float*)d_in[3];
  const float* bsp = (const float*)d_in[4];
  const float* tay = (const float*)d_in[5];
  const float* jac = (const float*)d_in[6];
  const float* che = (const float*)d_in[7];
  const float* fou = (const float*)d_in[8];
  const float* wav = (const float*)d_in[9];
  const float* wsc = (const float*)d_in[10];
  const float* wsh = (const float*)d_in[11];
  const float* gns = (const float*)d_in[12];
  const float* alp = (const float*)d_in[13];
  const float* bet = (const float*)d_in[14];
  const float* mxl = (const float*)d_in[15];
  float* out = (float*)d_out;

  uint8_t* w = (uint8_t*)d_ws;
  float* pmin = (float*)(w + OFF_PMIN);
  float* pmax = (float*)(w + OFF_PMAX);
  unsigned short* Csw = (unsigned short*)(w + OFF_CSW);

  k_prep<<<72, 256, 0, stream>>>(X, bv, bg, bsp, tay, jac, che, fou, wav,
                                 gns, alp, bet, mxl, pmin, pmax, Csw);
  k_main<<<512, 256, 0, stream>>>(X, Csw, pmin, pmax, wsc, wsh, alp, bbi, out);
}